// Round 1
// baseline (882.797 us; speedup 1.0000x reference)
//
#include <hip/hip_runtime.h>

// Problem constants
#define NN 128
#define CC 64          // C_IN == C_OUT
#define TT 256
#define VV 25
#define NSUB 3
#define TCH 8                  // t-rows per block
#define LPOS (TCH*VV)          // 200 positions per block tile
#define NCHUNK (TT/TCH)        // 32 chunks per n
#define CNT (NN*TT*VV)         // 819200 positions per channel

// workspace layout (float offsets)
#define WS_SBUF 0       // 75:  S_i[v] rowsums
#define WS_BEFF 80      // 64:  b_eff
#define WS_GSUM 144     // 64:  global sum of y (hidden minus bias)
#define WS_GSQ  208     // 64:  global sum of y^2
#define WS_W    272     // 25*64*64: W_eff then (in-place) M_fin, layout [v][c][o]
#define WS_BFIN 102672  // 64:  folded bias
// total ~411 KB of d_ws

__global__ void k_rowsum(const float* __restrict__ A, const float* __restrict__ ga,
                         float* __restrict__ ws) {
    int t = threadIdx.x;
    if (t < NSUB*VV) {
        int i = t / VV, v = t % VV;
        const float* pa = A  + (i*VV + v)*VV;
        const float* pg = ga + (i*VV + v)*VV;
        float s = 0.f;
        for (int w = 0; w < VV; ++w) s += pa[w] + pg[w];
        ws[WS_SBUF + t] = s;
    }
}

// build W_eff[v][c][o] = sum_i g_w[i][o][c] * (1 + S_i[v]);   25*64*64 = 102400 threads
__global__ void k_weff(const float* __restrict__ gw, const float* __restrict__ gb,
                       float* __restrict__ ws) {
    int idx = blockIdx.x*256 + threadIdx.x;
    int v = idx >> 12;
    int c = (idx >> 6) & 63;
    int o = idx & 63;
    float acc = 0.f;
    #pragma unroll
    for (int i = 0; i < NSUB; ++i)
        acc = fmaf(gw[(i*CC + o)*CC + c], 1.f + ws[WS_SBUF + i*VV + v], acc);
    ws[WS_W + idx] = acc;
    if (blockIdx.x == 0 && threadIdx.x < CC) {
        int oo = threadIdx.x;
        ws[WS_BEFF + oo] = gb[oo] + gb[CC + oo] + gb[2*CC + oo];
    }
}

// stats pass: accumulate sum and sumsq of y[n,o,t,v] = sum_c W_eff[v][c][o]*x[n,c,t,v]
__global__ __launch_bounds__(256) void k_stats(const float* __restrict__ x,
                                               const float* __restrict__ wsw,
                                               float* __restrict__ gsum,
                                               float* __restrict__ gsq) {
    __shared__ __align__(16) float Xs[CC*LPOS];   // [c][200]
    __shared__ float s_sum[CC], s_sq[CC];
    int tid = threadIdx.x;
    int n = blockIdx.x >> 5;
    int ch = blockIdx.x & 31;
    const float* xb = x + (size_t)n*(CC*TT*VV) + ch*LPOS;
    // coalesced stage: float4 global reads, float4 LDS writes (conflict-free)
    for (int i4 = tid; i4 < CC*(LPOS/4); i4 += 256) {
        int c = i4 / (LPOS/4), j4 = i4 % (LPOS/4);
        *(float4*)(&Xs[c*LPOS + j4*4]) = *(const float4*)(xb + c*(TT*VV) + j4*4);
    }
    if (tid < CC) { s_sum[tid] = 0.f; s_sq[tid] = 0.f; }
    __syncthreads();
    if (tid < 200) {
        int v = tid % VV, og = tid / VV, o0 = og*8;
        float acc[8][8];
        #pragma unroll
        for (int a = 0; a < 8; ++a)
            #pragma unroll
            for (int b = 0; b < 8; ++b) acc[a][b] = 0.f;
        const float* wp = wsw + v*(CC*CC) + o0;   // [v][c][o]
        #pragma unroll 2
        for (int c = 0; c < CC; ++c) {
            float4 w0 = *(const float4*)(wp + c*CC);
            float4 w1 = *(const float4*)(wp + c*CC + 4);
            float xv[TCH];
            #pragma unroll
            for (int tl = 0; tl < TCH; ++tl) xv[tl] = Xs[c*LPOS + tl*VV + v];
            #pragma unroll
            for (int tl = 0; tl < TCH; ++tl) {
                float xx = xv[tl];
                acc[tl][0] = fmaf(xx, w0.x, acc[tl][0]);
                acc[tl][1] = fmaf(xx, w0.y, acc[tl][1]);
                acc[tl][2] = fmaf(xx, w0.z, acc[tl][2]);
                acc[tl][3] = fmaf(xx, w0.w, acc[tl][3]);
                acc[tl][4] = fmaf(xx, w1.x, acc[tl][4]);
                acc[tl][5] = fmaf(xx, w1.y, acc[tl][5]);
                acc[tl][6] = fmaf(xx, w1.z, acc[tl][6]);
                acc[tl][7] = fmaf(xx, w1.w, acc[tl][7]);
            }
        }
        #pragma unroll
        for (int oi = 0; oi < 8; ++oi) {
            float s1 = 0.f, s2 = 0.f;
            #pragma unroll
            for (int tl = 0; tl < TCH; ++tl) {
                s1 += acc[tl][oi];
                s2 = fmaf(acc[tl][oi], acc[tl][oi], s2);
            }
            atomicAdd(&s_sum[o0+oi], s1);
            atomicAdd(&s_sq[o0+oi], s2);
        }
    }
    __syncthreads();
    if (tid < CC) {
        atomicAdd(&gsum[tid], s_sum[tid]);
        atomicAdd(&gsq[tid], s_sq[tid]);
    }
}

// fold BN into the matrix in-place: M = alpha*W_eff + I; b_fin = beta + alpha*(b_eff - mean)
__global__ void k_mid(float* __restrict__ ws, const float* __restrict__ gamma,
                      const float* __restrict__ beta) {
    int idx = blockIdx.x*256 + threadIdx.x;
    int c = (idx >> 6) & 63;
    int o = idx & 63;
    float b     = ws[WS_BEFF + o];
    float meanY = ws[WS_GSUM + o] * (1.f/CNT);
    float ey2   = ws[WS_GSQ  + o] * (1.f/CNT);
    float m   = meanY + b;                          // E[hidden]
    float var = ey2 + 2.f*b*meanY + b*b - m*m;      // E[hidden^2] - E[hidden]^2 (biased)
    float alpha = gamma[o] * rsqrtf(var + 1e-5f);
    float wv = ws[WS_W + idx];
    ws[WS_W + idx] = fmaf(alpha, wv, (c == o) ? 1.f : 0.f);  // fold identity residual
    if (blockIdx.x == 0 && threadIdx.x < CC)
        ws[WS_BFIN + o] = fmaf(alpha, b - m, beta[o]);
}

// final pass: out = relu( sum_c M[v][c][o]*x + b_fin[o] )
__global__ __launch_bounds__(256) void k_final(const float* __restrict__ x,
                                               const float* __restrict__ ws,
                                               float* __restrict__ out) {
    __shared__ __align__(16) float Xs[CC*LPOS];
    int tid = threadIdx.x;
    int n = blockIdx.x >> 5;
    int ch = blockIdx.x & 31;
    const float* xb = x + (size_t)n*(CC*TT*VV) + ch*LPOS;
    for (int i4 = tid; i4 < CC*(LPOS/4); i4 += 256) {
        int c = i4 / (LPOS/4), j4 = i4 % (LPOS/4);
        *(float4*)(&Xs[c*LPOS + j4*4]) = *(const float4*)(xb + c*(TT*VV) + j4*4);
    }
    __syncthreads();
    if (tid < 200) {
        int v = tid % VV, og = tid / VV, o0 = og*8;
        float acc[8][8];
        #pragma unroll
        for (int a = 0; a < 8; ++a)
            #pragma unroll
            for (int b = 0; b < 8; ++b) acc[a][b] = 0.f;
        const float* wp = ws + WS_W + v*(CC*CC) + o0;
        #pragma unroll 2
        for (int c = 0; c < CC; ++c) {
            float4 w0 = *(const float4*)(wp + c*CC);
            float4 w1 = *(const float4*)(wp + c*CC + 4);
            float xv[TCH];
            #pragma unroll
            for (int tl = 0; tl < TCH; ++tl) xv[tl] = Xs[c*LPOS + tl*VV + v];
            #pragma unroll
            for (int tl = 0; tl < TCH; ++tl) {
                float xx = xv[tl];
                acc[tl][0] = fmaf(xx, w0.x, acc[tl][0]);
                acc[tl][1] = fmaf(xx, w0.y, acc[tl][1]);
                acc[tl][2] = fmaf(xx, w0.z, acc[tl][2]);
                acc[tl][3] = fmaf(xx, w0.w, acc[tl][3]);
                acc[tl][4] = fmaf(xx, w1.x, acc[tl][4]);
                acc[tl][5] = fmaf(xx, w1.y, acc[tl][5]);
                acc[tl][6] = fmaf(xx, w1.z, acc[tl][6]);
                acc[tl][7] = fmaf(xx, w1.w, acc[tl][7]);
            }
        }
        float bf[8];
        #pragma unroll
        for (int oi = 0; oi < 8; ++oi) bf[oi] = ws[WS_BFIN + o0 + oi];
        float* ob = out + (size_t)n*(CC*TT*VV) + ch*LPOS + v;
        #pragma unroll
        for (int oi = 0; oi < 8; ++oi) {
            #pragma unroll
            for (int tl = 0; tl < TCH; ++tl) {
                float val = acc[tl][oi] + bf[oi];
                ob[(o0+oi)*(TT*VV) + tl*VV] = fmaxf(val, 0.f);
            }
        }
    }
}

extern "C" void kernel_launch(void* const* d_in, const int* in_sizes, int n_in,
                              void* d_out, int out_size, void* d_ws, size_t ws_size,
                              hipStream_t stream) {
    const float* x     = (const float*)d_in[0];
    const float* A     = (const float*)d_in[1];
    const float* ga    = (const float*)d_in[2];
    // d_in[3..6] = a_w, a_b, b_w, b_b: provably unused (softmax over contracted axis sums to 1)
    const float* gw    = (const float*)d_in[7];
    const float* gb    = (const float*)d_in[8];
    const float* gamma = (const float*)d_in[9];
    const float* beta  = (const float*)d_in[10];
    float* ws  = (float*)d_ws;
    float* out = (float*)d_out;

    hipLaunchKernelGGL(k_rowsum, dim3(1), dim3(128), 0, stream, A, ga, ws);
    hipLaunchKernelGGL(k_weff, dim3(400), dim3(256), 0, stream, gw, gb, ws);
    hipMemsetAsync(ws + WS_GSUM, 0, 128*sizeof(float), stream);   // zero gsum+gsq
    hipLaunchKernelGGL(k_stats, dim3(NN*NCHUNK), dim3(256), 0, stream,
                       x, ws + WS_W, ws + WS_GSUM, ws + WS_GSQ);
    hipLaunchKernelGGL(k_mid, dim3(400), dim3(256), 0, stream, ws, gamma, beta);
    hipLaunchKernelGGL(k_final, dim3(NN*NCHUNK), dim3(256), 0, stream, x, ws, out);
}